// Round 14
// baseline (315.293 us; speedup 1.0000x reference)
//
#include <hip/hip_runtime.h>
#include <stdint.h>

#define NN 8192
#define FIN 128
#define FH 64
#define FO 16
#define BM 64
#define BN 64
#define SPLIT1 4
#define NRANGE1 (NN / SPLIT1)   // 2048
#define NCHUNK1 (NRANGE1 / BN)  // 32
#define SPLIT2 16
#define NRANGE2 (NN / SPLIT2)   // 512

typedef float    f32x4 __attribute__((ext_vector_type(4)));
typedef float    f32x2 __attribute__((ext_vector_type(2)));
typedef _Float16 f16x8 __attribute__((ext_vector_type(8)));
typedef _Float16 h2    __attribute__((ext_vector_type(2)));

union U8 { f16x8 v; h2 p[4]; };

#if defined(__has_builtin)
#if __has_builtin(__builtin_amdgcn_cvt_pk_fp8_f32) && __has_builtin(__builtin_amdgcn_cvt_pk_f32_fp8)
#define HAVE_HW_FP8 1
#endif
#endif

static __device__ __forceinline__ void fma4(float4& acc, float a, const float4 s) {
  acc.x = fmaf(a, s.x, acc.x);
  acc.y = fmaf(a, s.y, acc.y);
  acc.z = fmaf(a, s.z, acc.z);
  acc.w = fmaf(a, s.w, acc.w);
}

static __device__ __forceinline__ float dot2(h2 a, h2 b, float c) {
#if defined(__has_builtin)
#if __has_builtin(__builtin_amdgcn_fdot2)
  return __builtin_amdgcn_fdot2(a, b, c, false);
#else
  return c + (float)a.x * (float)b.x + (float)a.y * (float)b.y;
#endif
#else
  return c + (float)a.x * (float)b.x + (float)a.y * (float)b.y;
#endif
}

#ifndef HAVE_HW_FP8
static __device__ __forceinline__ uint32_t enc1(float f) {
  uint32_t b = __float_as_uint(f), s = (b >> 31) << 7;
  float a = fabsf(f);
  if (a < 0.001953125f) return s;
  if (a > 448.f) a = 448.f;
  uint32_t u = __float_as_uint(a) + 0x00080000u;
  int e = (int)(u >> 23) - 127 + 7;
  uint32_t m = (u >> 20) & 7;
  if (e < 1) return s;
  if (e >= 16 || (e == 15 && m == 7)) { e = 15; m = 6; }
  return s | ((uint32_t)e << 3) | m;
}
static __device__ __forceinline__ float dec1(uint32_t q) {
  uint32_t s = q >> 7, e = (q >> 3) & 15, m = q & 7;
  float v = (e == 0) ? (float)m * 0.001953125f
                     : ldexpf((float)(8 + m) * 0.125f, (int)e - 7);
  return s ? -v : v;
}
#endif

static __device__ __forceinline__ uint32_t pack4_fp8(float d0, float d1, float d2, float d3) {
#ifdef HAVE_HW_FP8
  int pk = __builtin_amdgcn_cvt_pk_fp8_f32(d0, d1, 0, false);
  pk = __builtin_amdgcn_cvt_pk_fp8_f32(d2, d3, pk, true);
  return (uint32_t)pk;
#else
  return enc1(d0) | (enc1(d1) << 8) | (enc1(d2) << 16) | (enc1(d3) << 24);
#endif
}

static __device__ __forceinline__ f16x8 dec8_fp8(uint2 u) {
  U8 r;
#ifdef HAVE_HW_FP8
  f32x2 a = __builtin_amdgcn_cvt_pk_f32_fp8((int)u.x, false);
  f32x2 b = __builtin_amdgcn_cvt_pk_f32_fp8((int)u.x, true);
  f32x2 c = __builtin_amdgcn_cvt_pk_f32_fp8((int)u.y, false);
  f32x2 d = __builtin_amdgcn_cvt_pk_f32_fp8((int)u.y, true);
  r.p[0].x = (_Float16)a.x; r.p[0].y = (_Float16)a.y;
  r.p[1].x = (_Float16)b.x; r.p[1].y = (_Float16)b.y;
  r.p[2].x = (_Float16)c.x; r.p[2].y = (_Float16)c.y;
  r.p[3].x = (_Float16)d.x; r.p[3].y = (_Float16)d.y;
#else
#pragma unroll
  for (int k = 0; k < 4; ++k) {
    uint32_t w = (k < 2) ? u.x : u.y;
    uint32_t sh = (k & 1) ? 16 : 0;
    r.p[k].x = (_Float16)dec1((w >> sh) & 0xff);
    r.p[k].y = (_Float16)dec1((w >> (sh + 8)) & 0xff);
  }
#endif
  return r.v;
}

// ---------------- S1p = pack_fp16_pairs(x @ W1)  -> [np][j][2] layout ----------------
__global__ __launch_bounds__(256) void k_s1(const float* __restrict__ x,
                                            const float* __restrict__ W1,
                                            _Float16* __restrict__ S1p) {
  __shared__ float W1l[FIN * FH];
  __shared__ float xl[16][FIN + 4];
  __shared__ float hl[16][FH];
  const int t = threadIdx.x;
  const int n0 = blockIdx.x * 16;
  for (int i = t; i < FIN * FH / 4; i += 256)
    ((float4*)W1l)[i] = ((const float4*)W1)[i];
  for (int i = t; i < 16 * FIN; i += 256) {
    int r = i >> 7, c = i & (FIN - 1);
    xl[r][c] = x[(size_t)(n0 + r) * FIN + c];
  }
  __syncthreads();
  const int m = t >> 4;
  const int j0 = (t & 15) << 2;
  float4 acc = {0.f, 0.f, 0.f, 0.f};
#pragma unroll 8
  for (int k = 0; k < FIN; ++k) {
    float xv = xl[m][k];
    float4 w = *(const float4*)&W1l[k * FH + j0];
    fma4(acc, xv, w);
  }
  *(float4*)&hl[m][j0] = acc;
  __syncthreads();
  const int j = t & 63;
  const int g = t >> 6;
#pragma unroll
  for (int e = 0; e < 2; ++e) {
    const int np = g * 2 + e;
    h2 v;
    v.x = (_Float16)hl[np * 2 + 0][j];
    v.y = (_Float16)hl[np * 2 + 1][j];
    *(h2*)&S1p[(((size_t)(n0 >> 1) + np) * FH + j) * 2] = v;
  }
}

// ===== pass 1 (FUSED): pair-transposed uint2 A2 stores (full 128B line segments) =====
__global__ __launch_bounds__(256) void k_pass1_fused(const float* __restrict__ adj,
                                                     const _Float16* __restrict__ S1p,
                                                     const float* __restrict__ pi1,
                                                     const float* __restrict__ pi2,
                                                     float* __restrict__ hpart,
                                                     uint32_t* __restrict__ A2q) {
  __shared__ h2 Alds[2][BN / 2][BM];          // double-buffered, 8 KB each
  __shared__ _Float16 S1l[2][BN / 2][FH][2];  // double-buffered, 8 KB each
  const int t = threadIdx.x;
  const int mb = blockIdx.x >> 2;
  const int sp = blockIdx.x & 3;

  float p0 = pi1[0], p1 = pi1[1], p2 = pi1[2], p3 = pi1[3];
  float mx = fmaxf(fmaxf(p0, p1), fmaxf(p2, p3));
  float e0 = expf(p0 - mx), e1 = expf(p1 - mx), e2 = expf(p2 - mx), e3 = expf(p3 - mx);
  float inv = 1.0f / (e0 + e1 + e2 + e3);
  const float w0 = e0 * inv, w1 = e1 * inv, w2 = e2 * inv, w3 = e3 * inv;
  const float v0 = pi2[0], v1 = pi2[1], v2 = pi2[2], v3 = pi2[3];   // raw pi2

  const size_t NN2 = (size_t)NN * NN;
  const size_t NNq = (size_t)NN / 4;
  const size_t row0 = (size_t)mb * BM;
  const int nbase = sp * NRANGE1;

  const int n4 = t & 15;           // n-quad (staging)
  const int ms = t >> 4;           // row slot (staging), row = ms + 16*p
  const int m0 = (t & 15) << 2;    // compute: 4 rows
  const int j0 = (t >> 4) << 2;    // compute: 4 cols

  f32x4 pf[4][4];
  f16x8 pfS[2];
  uint32_t pk4[4];                 // current chunk's packed fp8
  uint32_t pkprev[4];              // even-chunk's packed fp8 (pair buffer)

  float4 acc0 = {0,0,0,0}, acc1 = {0,0,0,0}, acc2 = {0,0,0,0}, acc3 = {0,0,0,0};

  auto ISSUE = [&](int c) {
    const int n0 = nbase + c * BN;
#pragma unroll
    for (int p = 0; p < 4; ++p) {
      const float* g = adj + (row0 + (size_t)(ms + (p << 4))) * NN + (size_t)(n0 + (n4 << 2));
      pf[p][0] = __builtin_nontemporal_load((const f32x4*)g);
      pf[p][1] = __builtin_nontemporal_load((const f32x4*)(g + NN2));
      pf[p][2] = __builtin_nontemporal_load((const f32x4*)(g + 2 * NN2));
      pf[p][3] = __builtin_nontemporal_load((const f32x4*)(g + 3 * NN2));
    }
    const f16x8* src = (const f16x8*)(S1p + (size_t)(n0 >> 1) * FH * 2);
    pfS[0] = src[t];
    pfS[1] = src[t + 256];
  };

  auto STAGE = [&](h2 (&Ab)[BN / 2][BM], _Float16 (&Sb)[BN / 2][FH][2]) {
#pragma unroll
    for (int p = 0; p < 4; ++p) {
      const int ml = ms + (p << 4);
      f32x4 a0 = pf[p][0], a1 = pf[p][1], a2 = pf[p][2], a3 = pf[p][3];
      float c0 = fmaf(w0, a0.x, fmaf(w1, a1.x, fmaf(w2, a2.x, w3 * a3.x)));
      float c1 = fmaf(w0, a0.y, fmaf(w1, a1.y, fmaf(w2, a2.y, w3 * a3.y)));
      float c2 = fmaf(w0, a0.z, fmaf(w1, a1.z, fmaf(w2, a2.z, w3 * a3.z)));
      float c3 = fmaf(w0, a0.w, fmaf(w1, a1.w, fmaf(w2, a2.w, w3 * a3.w)));
      const int np0 = n4 * 2, np1 = np0 + 1;
      h2 u01; u01.x = (_Float16)c0; u01.y = (_Float16)c1;
      h2 u23; u23.x = (_Float16)c2; u23.y = (_Float16)c3;
      Ab[np0][ml ^ ((np0 & 7) << 2)] = u01;
      Ab[np1][ml ^ ((np1 & 7) << 2)] = u23;
      float d0 = fmaf(v0, a0.x, fmaf(v1, a1.x, fmaf(v2, a2.x, v3 * a3.x)));
      float d1 = fmaf(v0, a0.y, fmaf(v1, a1.y, fmaf(v2, a2.y, v3 * a3.y)));
      float d2 = fmaf(v0, a0.z, fmaf(v1, a1.z, fmaf(v2, a2.z, v3 * a3.z)));
      float d3 = fmaf(v0, a0.w, fmaf(v1, a1.w, fmaf(v2, a2.w, v3 * a3.w)));
      pk4[p] = pack4_fp8(d0, d1, d2, d3);        // defer the store (pair-buffered)
    }
    f16x8* dst = (f16x8*)&Sb[0][0][0];
    dst[t]       = pfS[0];
    dst[t + 256] = pfS[1];
  };

  // Store a chunk PAIR, lane-transposed so each lane writes uint2 (8B) and each
  // 16-lane row-group writes 128B contiguous (full line). Values bit-identical
  // to per-chunk 4B stores. Shuffles stay within same-row 16-lane groups.
  auto STORE_A2W = [&](int ce) {   // ce = even chunk index of the pair
    const int n0e = nbase + ce * BN;
    const int base = t & ~15;
    const int m = n4 & 7;
    const bool hi = n4 >= 8;
#pragma unroll
    for (int p = 0; p < 4; ++p) {
      const int ml = ms + (p << 4);
      uint32_t pa0 = (uint32_t)__shfl((int)pkprev[p], base | (2 * m),     64);
      uint32_t pa1 = (uint32_t)__shfl((int)pkprev[p], base | (2 * m + 1), 64);
      uint32_t pb0 = (uint32_t)__shfl((int)pk4[p],    base | (2 * m),     64);
      uint32_t pb1 = (uint32_t)__shfl((int)pk4[p],    base | (2 * m + 1), 64);
      uint2 u;
      u.x = hi ? pb0 : pa0;
      u.y = hi ? pb1 : pa1;
      *(uint2*)(A2q + (row0 + (size_t)ml) * NNq + (size_t)((n0e >> 2) + n4 * 2)) = u;
    }
  };

  ISSUE(0);
  for (int c = 0; c < NCHUNK1; c += 2) {
    // even chunk: stage, issue next, hold pk in pkprev
    STAGE(Alds[0], S1l[0]);
    if (c + 1 < NCHUNK1) ISSUE(c + 1);
#pragma unroll
    for (int p = 0; p < 4; ++p) pkprev[p] = pk4[p];
    asm volatile("s_waitcnt lgkmcnt(0)" ::: "memory");
    __builtin_amdgcn_s_barrier();
#pragma unroll 4
    for (int np = 0; np < BN / 2; ++np) {
      const int s = (np & 7) << 2;
      U8 a;  a.v  = *(const f16x8*)&Alds[0][np][m0 ^ s];
      U8 sv; sv.v = *(const f16x8*)&S1l[0][np][j0][0];
      acc0.x = dot2(a.p[0], sv.p[0], acc0.x);
      acc0.y = dot2(a.p[0], sv.p[1], acc0.y);
      acc0.z = dot2(a.p[0], sv.p[2], acc0.z);
      acc0.w = dot2(a.p[0], sv.p[3], acc0.w);
      acc1.x = dot2(a.p[1], sv.p[0], acc1.x);
      acc1.y = dot2(a.p[1], sv.p[1], acc1.y);
      acc1.z = dot2(a.p[1], sv.p[2], acc1.z);
      acc1.w = dot2(a.p[1], sv.p[3], acc1.w);
      acc2.x = dot2(a.p[2], sv.p[0], acc2.x);
      acc2.y = dot2(a.p[2], sv.p[1], acc2.y);
      acc2.z = dot2(a.p[2], sv.p[2], acc2.z);
      acc2.w = dot2(a.p[2], sv.p[3], acc2.w);
      acc3.x = dot2(a.p[3], sv.p[0], acc3.x);
      acc3.y = dot2(a.p[3], sv.p[1], acc3.y);
      acc3.z = dot2(a.p[3], sv.p[2], acc3.z);
      acc3.w = dot2(a.p[3], sv.p[3], acc3.w);
    }

    // odd chunk: stage, issue next, wide-store the PAIR (after ISSUE: FIFO-young)
    STAGE(Alds[1], S1l[1]);
    if (c + 2 < NCHUNK1) ISSUE(c + 2);
    STORE_A2W(c);
    asm volatile("s_waitcnt lgkmcnt(0)" ::: "memory");
    __builtin_amdgcn_s_barrier();
#pragma unroll 4
    for (int np = 0; np < BN / 2; ++np) {
      const int s = (np & 7) << 2;
      U8 a;  a.v  = *(const f16x8*)&Alds[1][np][m0 ^ s];
      U8 sv; sv.v = *(const f16x8*)&S1l[1][np][j0][0];
      acc0.x = dot2(a.p[0], sv.p[0], acc0.x);
      acc0.y = dot2(a.p[0], sv.p[1], acc0.y);
      acc0.z = dot2(a.p[0], sv.p[2], acc0.z);
      acc0.w = dot2(a.p[0], sv.p[3], acc0.w);
      acc1.x = dot2(a.p[1], sv.p[0], acc1.x);
      acc1.y = dot2(a.p[1], sv.p[1], acc1.y);
      acc1.z = dot2(a.p[1], sv.p[2], acc1.z);
      acc1.w = dot2(a.p[1], sv.p[3], acc1.w);
      acc2.x = dot2(a.p[2], sv.p[0], acc2.x);
      acc2.y = dot2(a.p[2], sv.p[1], acc2.y);
      acc2.z = dot2(a.p[2], sv.p[2], acc2.z);
      acc2.w = dot2(a.p[2], sv.p[3], acc2.w);
      acc3.x = dot2(a.p[3], sv.p[0], acc3.x);
      acc3.y = dot2(a.p[3], sv.p[1], acc3.y);
      acc3.z = dot2(a.p[3], sv.p[2], acc3.z);
      acc3.w = dot2(a.p[3], sv.p[3], acc3.w);
    }
  }

  float* hp = hpart + (size_t)sp * NN * FH;
  const size_t rbase = (row0 + m0) * FH + j0;
  *(float4*)&hp[rbase]          = acc0;
  *(float4*)&hp[rbase + FH]     = acc1;
  *(float4*)&hp[rbase + 2 * FH] = acc2;
  *(float4*)&hp[rbase + 3 * FH] = acc3;
}

// ---------------- exact JAX threefry2x32 dropout (partitionable path), key=(0,42) ----------
__device__ __forceinline__ float dropout_scale(uint32_t e) {
  uint32_t x0 = 0u;
  uint32_t x1 = e;
  const uint32_t ks1 = 42u;
  const uint32_t ks2 = 0x1BD11BF0u;
  x1 += ks1;
#define TFR(d) { x0 += x1; x1 = (x1 << d) | (x1 >> (32 - d)); x1 ^= x0; }
  TFR(13) TFR(15) TFR(26) TFR(6)   x0 += ks1; x1 += ks2 + 1u;
  TFR(17) TFR(29) TFR(16) TFR(24)  x0 += ks2; x1 += 0u  + 2u;
  TFR(13) TFR(15) TFR(26) TFR(6)   x0 += 0u;  x1 += ks1 + 3u;
  TFR(17) TFR(29) TFR(16) TFR(24)  x0 += ks1; x1 += ks2 + 4u;
  TFR(13) TFR(15) TFR(26) TFR(6)   x0 += ks2; x1 += 0u  + 5u;
#undef TFR
  uint32_t bits = x0 ^ x1;
  float u = __uint_as_float((bits >> 9) | 0x3f800000u) - 1.0f;
  return (u < 0.7f) ? (1.0f / 0.7f) : 0.0f;
}

// ------- mid: h = dropout(relu(sum_sp hpart + b1)); HWT(fp16) = (h @ W2)^T ; also out = b2 -------
__global__ __launch_bounds__(256) void k_mid(const float* __restrict__ hpart,
                                             const float* __restrict__ b1,
                                             const float* __restrict__ W2,
                                             const float* __restrict__ b2,
                                             _Float16* __restrict__ HWT,
                                             float* __restrict__ out) {
  __shared__ float hl[4][FH];
  __shared__ float W2l[FH * FO];
  const int t = threadIdx.x;
  if (blockIdx.x < (NN * FO) / 256)
    out[blockIdx.x * 256 + t] = b2[t & 15];
  const int n0 = blockIdx.x << 2;
  for (int i = t; i < FH * FO; i += 256) W2l[i] = W2[i];
  const int j = t & 63, r = t >> 6;
  const uint32_t idx = (uint32_t)(n0 + r) * FH + j;
  const size_t NF = (size_t)NN * FH;
  float pre = b1[j];
#pragma unroll
  for (int s = 0; s < SPLIT1; ++s) pre += hpart[idx + (size_t)s * NF];
  float v = fmaxf(pre, 0.0f) * dropout_scale(idx);
  hl[r][j] = v;
  __syncthreads();
  if (t < 64) {
    const int rr = t >> 4, f = t & 15;
    float s = 0.f;
#pragma unroll 8
    for (int jj = 0; jj < FH; ++jj)
      s = fmaf(hl[rr][jj], W2l[jj * FO + f], s);
    HWT[(size_t)f * NN + (n0 + rr)] = (_Float16)s;
  }
}

// ===== pass 2 (dot2): out += A2q(fp8, regs) @ HWT(fp16, LDS) =====
__global__ __launch_bounds__(64) void k_pass2_dot(const uint32_t* __restrict__ A2q,
                                                  const _Float16* __restrict__ HWT,
                                                  float* __restrict__ out) {
  __shared__ f16x8 Htl[64 * 16];   // 16 KB
  const int t = threadIdx.x;       // 0..63
  const int mb = blockIdx.x >> 4;  // 0..127
  const int sp = blockIdx.x & 15;  // 0..15
  const size_t row0 = (size_t)mb * BM;
  const int nbase = sp * NRANGE2;
  const size_t NNq = (size_t)NN / 4;

#pragma unroll
  for (int i = 0; i < FO; ++i)
    Htl[t * FO + i] = *(const f16x8*)(HWT + (size_t)i * NN + nbase + t * 8);
  __syncthreads();

  const int fgrp = t & 3;
  const int mgrp = t >> 2;
  const size_t rbase = (row0 + (size_t)mgrp * 4) * NNq + (size_t)(nbase >> 2);

  float acc[4][4];
#pragma unroll
  for (int j = 0; j < 4; ++j)
#pragma unroll
    for (int i = 0; i < 4; ++i) acc[j][i] = 0.f;

  uint2 aA[4], aB[4];
#pragma unroll
  for (int j = 0; j < 4; ++j)
    aA[j] = *(const uint2*)(A2q + rbase + (size_t)j * NNq);

  auto LOADB = [&](int o) {
#pragma unroll
    for (int j = 0; j < 4; ++j)
      aB[j] = *(const uint2*)(A2q + rbase + (size_t)j * NNq + o * 2);
  };
  auto LOADA = [&](int o) {
#pragma unroll
    for (int j = 0; j < 4; ++j)
      aA[j] = *(const uint2*)(A2q + rbase + (size_t)j * NNq + o * 2);
  };

  auto COMPUTE = [&](const uint2* buf, int o) {
    U8 h0, h1, h2v, h3;
    h0.v  = Htl[o * FO + fgrp * 4 + 0];
    h1.v  = Htl[o * FO + fgrp * 4 + 1];
    h2v.v = Htl[o * FO + fgrp * 4 + 2];
    h3.v  = Htl[o * FO + fgrp * 4 + 3];
#pragma unroll
    for (int j = 0; j < 4; ++j) {
      U8 a;
      a.v = dec8_fp8(buf[j]);
#pragma unroll
      for (int q = 0; q < 4; ++q) {
        h2 pa = a.p[q];
        acc[j][0] = dot2(pa, h0.p[q],  acc[j][0]);
        acc[j][1] = dot2(pa, h1.p[q],  acc[j][1]);
        acc[j][2] = dot2(pa, h2v.p[q], acc[j][2]);
        acc[j][3] = dot2(pa, h3.p[q],  acc[j][3]);
      }
    }
  };

  for (int o = 0; o < 64; o += 2) {
    LOADB(o + 1);
    COMPUTE(aA, o);
    if (o + 2 < 64) LOADA(o + 2);
    COMPUTE(aB, o + 1);
  }

#pragma unroll
  for (int j = 0; j < 4; ++j)
#pragma unroll
    for (int i = 0; i < 4; ++i)
      atomicAdd(&out[(row0 + (size_t)mgrp * 4 + j) * FO + fgrp * 4 + i], acc[j][i]);
}

extern "C" void kernel_launch(void* const* d_in, const int* in_sizes, int n_in,
                              void* d_out, int out_size, void* d_ws, size_t ws_size,
                              hipStream_t stream) {
  const float* adj = (const float*)d_in[0];
  const float* x   = (const float*)d_in[1];
  const float* W1  = (const float*)d_in[2];
  const float* b1  = (const float*)d_in[3];
  const float* W2  = (const float*)d_in[4];
  const float* b2  = (const float*)d_in[5];
  const float* pi1 = (const float*)d_in[6];
  const float* pi2 = (const float*)d_in[7];
  float* out = (float*)d_out;
  float* ws  = (float*)d_ws;

  // ws layout: hpart f32[4*NN*FH] | S1p fp16[NN*FH] | A2q u32[NN*NN/4] | HWT fp16[FO*NN]  (~76 MB)
  float* hpart  = ws;
  _Float16* S1p = (_Float16*)(hpart + (size_t)SPLIT1 * NN * FH);
  uint32_t* A2q = (uint32_t*)(S1p + (size_t)NN * FH);
  _Float16* HWT = (_Float16*)(A2q + (size_t)NN * NN / 4);

  k_s1         <<<NN / 16,            256, 0, stream>>>(x, W1, S1p);
  k_pass1_fused<<<(NN / BM) * SPLIT1, 256, 0, stream>>>(adj, S1p, pi1, pi2, hpart, A2q);
  k_mid        <<<NN / 4,             256, 0, stream>>>(hpart, b1, W2, b2, HWT, out);
  k_pass2_dot  <<<(NN / BM) * SPLIT2,  64, 0, stream>>>(A2q, HWT, out);
}

// Round 15
// 296.276 us; speedup vs baseline: 1.0642x; 1.0642x over previous
//
#include <hip/hip_runtime.h>
#include <stdint.h>

#define NN 8192
#define FIN 128
#define FH 64
#define FO 16
#define BM 64
#define BN 64
#define SPLIT1 4
#define NRANGE1 (NN / SPLIT1)   // 2048
#define NCHUNK1 (NRANGE1 / BN)  // 32
#define SPLIT2 16
#define NRANGE2 (NN / SPLIT2)   // 512

typedef float    f32x4 __attribute__((ext_vector_type(4)));
typedef float    f32x2 __attribute__((ext_vector_type(2)));
typedef _Float16 f16x8 __attribute__((ext_vector_type(8)));
typedef _Float16 h2    __attribute__((ext_vector_type(2)));

union U8 { f16x8 v; h2 p[4]; };

#if defined(__has_builtin)
#if __has_builtin(__builtin_amdgcn_cvt_pk_fp8_f32) && __has_builtin(__builtin_amdgcn_cvt_pk_f32_fp8)
#define HAVE_HW_FP8 1
#endif
#endif

static __device__ __forceinline__ void fma4(float4& acc, float a, const float4 s) {
  acc.x = fmaf(a, s.x, acc.x);
  acc.y = fmaf(a, s.y, acc.y);
  acc.z = fmaf(a, s.z, acc.z);
  acc.w = fmaf(a, s.w, acc.w);
}

static __device__ __forceinline__ float dot2(h2 a, h2 b, float c) {
#if defined(__has_builtin)
#if __has_builtin(__builtin_amdgcn_fdot2)
  return __builtin_amdgcn_fdot2(a, b, c, false);
#else
  return c + (float)a.x * (float)b.x + (float)a.y * (float)b.y;
#endif
#else
  return c + (float)a.x * (float)b.x + (float)a.y * (float)b.y;
#endif
}

#ifndef HAVE_HW_FP8
static __device__ __forceinline__ uint32_t enc1(float f) {
  uint32_t b = __float_as_uint(f), s = (b >> 31) << 7;
  float a = fabsf(f);
  if (a < 0.001953125f) return s;
  if (a > 448.f) a = 448.f;
  uint32_t u = __float_as_uint(a) + 0x00080000u;
  int e = (int)(u >> 23) - 127 + 7;
  uint32_t m = (u >> 20) & 7;
  if (e < 1) return s;
  if (e >= 16 || (e == 15 && m == 7)) { e = 15; m = 6; }
  return s | ((uint32_t)e << 3) | m;
}
static __device__ __forceinline__ float dec1(uint32_t q) {
  uint32_t s = q >> 7, e = (q >> 3) & 15, m = q & 7;
  float v = (e == 0) ? (float)m * 0.001953125f
                     : ldexpf((float)(8 + m) * 0.125f, (int)e - 7);
  return s ? -v : v;
}
#endif

static __device__ __forceinline__ uint32_t pack4_fp8(float d0, float d1, float d2, float d3) {
#ifdef HAVE_HW_FP8
  int pk = __builtin_amdgcn_cvt_pk_fp8_f32(d0, d1, 0, false);
  pk = __builtin_amdgcn_cvt_pk_fp8_f32(d2, d3, pk, true);
  return (uint32_t)pk;
#else
  return enc1(d0) | (enc1(d1) << 8) | (enc1(d2) << 16) | (enc1(d3) << 24);
#endif
}

static __device__ __forceinline__ f16x8 dec8_fp8(uint2 u) {
  U8 r;
#ifdef HAVE_HW_FP8
  f32x2 a = __builtin_amdgcn_cvt_pk_f32_fp8((int)u.x, false);
  f32x2 b = __builtin_amdgcn_cvt_pk_f32_fp8((int)u.x, true);
  f32x2 c = __builtin_amdgcn_cvt_pk_f32_fp8((int)u.y, false);
  f32x2 d = __builtin_amdgcn_cvt_pk_f32_fp8((int)u.y, true);
  r.p[0].x = (_Float16)a.x; r.p[0].y = (_Float16)a.y;
  r.p[1].x = (_Float16)b.x; r.p[1].y = (_Float16)b.y;
  r.p[2].x = (_Float16)c.x; r.p[2].y = (_Float16)c.y;
  r.p[3].x = (_Float16)d.x; r.p[3].y = (_Float16)d.y;
#else
#pragma unroll
  for (int k = 0; k < 4; ++k) {
    uint32_t w = (k < 2) ? u.x : u.y;
    uint32_t sh = (k & 1) ? 16 : 0;
    r.p[k].x = (_Float16)dec1((w >> sh) & 0xff);
    r.p[k].y = (_Float16)dec1((w >> (sh + 8)) & 0xff);
  }
#endif
  return r.v;
}

// ---------------- S1p = pack_fp16_pairs(x @ W1)  -> [np][j][2] layout ----------------
__global__ __launch_bounds__(256) void k_s1(const float* __restrict__ x,
                                            const float* __restrict__ W1,
                                            _Float16* __restrict__ S1p) {
  __shared__ float W1l[FIN * FH];
  __shared__ float xl[16][FIN + 4];
  __shared__ float hl[16][FH];
  const int t = threadIdx.x;
  const int n0 = blockIdx.x * 16;
  for (int i = t; i < FIN * FH / 4; i += 256)
    ((float4*)W1l)[i] = ((const float4*)W1)[i];
  for (int i = t; i < 16 * FIN; i += 256) {
    int r = i >> 7, c = i & (FIN - 1);
    xl[r][c] = x[(size_t)(n0 + r) * FIN + c];
  }
  __syncthreads();
  const int m = t >> 4;
  const int j0 = (t & 15) << 2;
  float4 acc = {0.f, 0.f, 0.f, 0.f};
#pragma unroll 8
  for (int k = 0; k < FIN; ++k) {
    float xv = xl[m][k];
    float4 w = *(const float4*)&W1l[k * FH + j0];
    fma4(acc, xv, w);
  }
  *(float4*)&hl[m][j0] = acc;
  __syncthreads();
  const int j = t & 63;
  const int g = t >> 6;
#pragma unroll
  for (int e = 0; e < 2; ++e) {
    const int np = g * 2 + e;
    h2 v;
    v.x = (_Float16)hl[np * 2 + 0][j];
    v.y = (_Float16)hl[np * 2 + 1][j];
    *(h2*)&S1p[(((size_t)(n0 >> 1) + np) * FH + j) * 2] = v;
  }
}

// ===== pass 1 (FUSED): A2 stores issued mid-COMPUTE (overlap VALU, stay FIFO-young) =====
__global__ __launch_bounds__(256) void k_pass1_fused(const float* __restrict__ adj,
                                                     const _Float16* __restrict__ S1p,
                                                     const float* __restrict__ pi1,
                                                     const float* __restrict__ pi2,
                                                     float* __restrict__ hpart,
                                                     uint32_t* __restrict__ A2q) {
  __shared__ h2 Alds[2][BN / 2][BM];          // double-buffered, 8 KB each
  __shared__ _Float16 S1l[2][BN / 2][FH][2];  // double-buffered, 8 KB each
  const int t = threadIdx.x;
  const int mb = blockIdx.x >> 2;
  const int sp = blockIdx.x & 3;

  float p0 = pi1[0], p1 = pi1[1], p2 = pi1[2], p3 = pi1[3];
  float mx = fmaxf(fmaxf(p0, p1), fmaxf(p2, p3));
  float e0 = expf(p0 - mx), e1 = expf(p1 - mx), e2 = expf(p2 - mx), e3 = expf(p3 - mx);
  float inv = 1.0f / (e0 + e1 + e2 + e3);
  const float w0 = e0 * inv, w1 = e1 * inv, w2 = e2 * inv, w3 = e3 * inv;
  const float v0 = pi2[0], v1 = pi2[1], v2 = pi2[2], v3 = pi2[3];   // raw pi2

  const size_t NN2 = (size_t)NN * NN;
  const size_t NNq = (size_t)NN / 4;
  const size_t row0 = (size_t)mb * BM;
  const int nbase = sp * NRANGE1;

  const int n4 = t & 15;           // n-quad (staging)
  const int ms = t >> 4;           // row slot (staging), row = ms + 16*p
  const int m0 = (t & 15) << 2;    // compute: 4 rows
  const int j0 = (t >> 4) << 2;    // compute: 4 cols

  f32x4 pf[4][4];
  f16x8 pfS[2];
  uint32_t pk4[4];                 // deferred A2 store data (chunk-local)

  float4 acc0 = {0,0,0,0}, acc1 = {0,0,0,0}, acc2 = {0,0,0,0}, acc3 = {0,0,0,0};

  auto ISSUE = [&](int c) {
    const int n0 = nbase + c * BN;
#pragma unroll
    for (int p = 0; p < 4; ++p) {
      const float* g = adj + (row0 + (size_t)(ms + (p << 4))) * NN + (size_t)(n0 + (n4 << 2));
      pf[p][0] = __builtin_nontemporal_load((const f32x4*)g);
      pf[p][1] = __builtin_nontemporal_load((const f32x4*)(g + NN2));
      pf[p][2] = __builtin_nontemporal_load((const f32x4*)(g + 2 * NN2));
      pf[p][3] = __builtin_nontemporal_load((const f32x4*)(g + 3 * NN2));
    }
    const f16x8* src = (const f16x8*)(S1p + (size_t)(n0 >> 1) * FH * 2);
    pfS[0] = src[t];
    pfS[1] = src[t + 256];
  };

  auto STAGE = [&](h2 (&Ab)[BN / 2][BM], _Float16 (&Sb)[BN / 2][FH][2]) {
#pragma unroll
    for (int p = 0; p < 4; ++p) {
      const int ml = ms + (p << 4);
      f32x4 a0 = pf[p][0], a1 = pf[p][1], a2 = pf[p][2], a3 = pf[p][3];
      float c0 = fmaf(w0, a0.x, fmaf(w1, a1.x, fmaf(w2, a2.x, w3 * a3.x)));
      float c1 = fmaf(w0, a0.y, fmaf(w1, a1.y, fmaf(w2, a2.y, w3 * a3.y)));
      float c2 = fmaf(w0, a0.z, fmaf(w1, a1.z, fmaf(w2, a2.z, w3 * a3.z)));
      float c3 = fmaf(w0, a0.w, fmaf(w1, a1.w, fmaf(w2, a2.w, w3 * a3.w)));
      const int np0 = n4 * 2, np1 = np0 + 1;
      h2 u01; u01.x = (_Float16)c0; u01.y = (_Float16)c1;
      h2 u23; u23.x = (_Float16)c2; u23.y = (_Float16)c3;
      Ab[np0][ml ^ ((np0 & 7) << 2)] = u01;
      Ab[np1][ml ^ ((np1 & 7) << 2)] = u23;
      float d0 = fmaf(v0, a0.x, fmaf(v1, a1.x, fmaf(v2, a2.x, v3 * a3.x)));
      float d1 = fmaf(v0, a0.y, fmaf(v1, a1.y, fmaf(v2, a2.y, v3 * a3.y)));
      float d2 = fmaf(v0, a0.z, fmaf(v1, a1.z, fmaf(v2, a2.z, v3 * a3.z)));
      float d3 = fmaf(v0, a0.w, fmaf(v1, a1.w, fmaf(v2, a2.w, v3 * a3.w)));
      pk4[p] = pack4_fp8(d0, d1, d2, d3);        // defer the store
    }
    f16x8* dst = (f16x8*)&Sb[0][0][0];
    dst[t]       = pfS[0];
    dst[t + 256] = pfS[1];
  };

  auto STORE_A2 = [&](int c) {   // issued mid-COMPUTE: FIFO-younger than chunk c+1 loads
    const int n0 = nbase + c * BN;
#pragma unroll
    for (int p = 0; p < 4; ++p) {
      const int ml = ms + (p << 4);
      A2q[(row0 + (size_t)ml) * NNq + (size_t)((n0 >> 2) + n4)] = pk4[p];  // normal (L2) store
    }
  };

#define COMPUTE_HALF(B, NP0, NP1)                                   \
  {                                                                 \
    _Pragma("unroll 4")                                             \
    for (int np = (NP0); np < (NP1); ++np) {                        \
      const int s = (np & 7) << 2;                                  \
      U8 a;  a.v  = *(const f16x8*)&Alds[B][np][m0 ^ s];            \
      U8 sv; sv.v = *(const f16x8*)&S1l[B][np][j0][0];              \
      acc0.x = dot2(a.p[0], sv.p[0], acc0.x);                       \
      acc0.y = dot2(a.p[0], sv.p[1], acc0.y);                       \
      acc0.z = dot2(a.p[0], sv.p[2], acc0.z);                       \
      acc0.w = dot2(a.p[0], sv.p[3], acc0.w);                       \
      acc1.x = dot2(a.p[1], sv.p[0], acc1.x);                       \
      acc1.y = dot2(a.p[1], sv.p[1], acc1.y);                       \
      acc1.z = dot2(a.p[1], sv.p[2], acc1.z);                       \
      acc1.w = dot2(a.p[1], sv.p[3], acc1.w);                       \
      acc2.x = dot2(a.p[2], sv.p[0], acc2.x);                       \
      acc2.y = dot2(a.p[2], sv.p[1], acc2.y);                       \
      acc2.z = dot2(a.p[2], sv.p[2], acc2.z);                       \
      acc2.w = dot2(a.p[2], sv.p[3], acc2.w);                       \
      acc3.x = dot2(a.p[3], sv.p[0], acc3.x);                       \
      acc3.y = dot2(a.p[3], sv.p[1], acc3.y);                       \
      acc3.z = dot2(a.p[3], sv.p[2], acc3.z);                       \
      acc3.w = dot2(a.p[3], sv.p[3], acc3.w);                       \
    }                                                               \
  }

  ISSUE(0);
  for (int c = 0; c < NCHUNK1; c += 2) {
    STAGE(Alds[0], S1l[0]);
    if (c + 1 < NCHUNK1) ISSUE(c + 1);
    asm volatile("s_waitcnt lgkmcnt(0)" ::: "memory");
    __builtin_amdgcn_s_barrier();
    COMPUTE_HALF(0, 0, 16)
    STORE_A2(c);                       // overlap store issue with dot2 VALU
    COMPUTE_HALF(0, 16, 32)

    STAGE(Alds[1], S1l[1]);
    if (c + 2 < NCHUNK1) ISSUE(c + 2);
    asm volatile("s_waitcnt lgkmcnt(0)" ::: "memory");
    __builtin_amdgcn_s_barrier();
    COMPUTE_HALF(1, 0, 16)
    STORE_A2(c + 1);
    COMPUTE_HALF(1, 16, 32)
  }
#undef COMPUTE_HALF

  float* hp = hpart + (size_t)sp * NN * FH;
  const size_t rbase = (row0 + m0) * FH + j0;
  *(float4*)&hp[rbase]          = acc0;
  *(float4*)&hp[rbase + FH]     = acc1;
  *(float4*)&hp[rbase + 2 * FH] = acc2;
  *(float4*)&hp[rbase + 3 * FH] = acc3;
}

// ---------------- exact JAX threefry2x32 dropout (partitionable path), key=(0,42) ----------
__device__ __forceinline__ float dropout_scale(uint32_t e) {
  uint32_t x0 = 0u;
  uint32_t x1 = e;
  const uint32_t ks1 = 42u;
  const uint32_t ks2 = 0x1BD11BF0u;
  x1 += ks1;
#define TFR(d) { x0 += x1; x1 = (x1 << d) | (x1 >> (32 - d)); x1 ^= x0; }
  TFR(13) TFR(15) TFR(26) TFR(6)   x0 += ks1; x1 += ks2 + 1u;
  TFR(17) TFR(29) TFR(16) TFR(24)  x0 += ks2; x1 += 0u  + 2u;
  TFR(13) TFR(15) TFR(26) TFR(6)   x0 += 0u;  x1 += ks1 + 3u;
  TFR(17) TFR(29) TFR(16) TFR(24)  x0 += ks1; x1 += ks2 + 4u;
  TFR(13) TFR(15) TFR(26) TFR(6)   x0 += ks2; x1 += 0u  + 5u;
#undef TFR
  uint32_t bits = x0 ^ x1;
  float u = __uint_as_float((bits >> 9) | 0x3f800000u) - 1.0f;
  return (u < 0.7f) ? (1.0f / 0.7f) : 0.0f;
}

// ------- mid: h = dropout(relu(sum_sp hpart + b1)); HWT(fp16) = (h @ W2)^T ; also out = b2 -------
__global__ __launch_bounds__(256) void k_mid(const float* __restrict__ hpart,
                                             const float* __restrict__ b1,
                                             const float* __restrict__ W2,
                                             const float* __restrict__ b2,
                                             _Float16* __restrict__ HWT,
                                             float* __restrict__ out) {
  __shared__ float hl[4][FH];
  __shared__ float W2l[FH * FO];
  const int t = threadIdx.x;
  if (blockIdx.x < (NN * FO) / 256)
    out[blockIdx.x * 256 + t] = b2[t & 15];
  const int n0 = blockIdx.x << 2;
  for (int i = t; i < FH * FO; i += 256) W2l[i] = W2[i];
  const int j = t & 63, r = t >> 6;
  const uint32_t idx = (uint32_t)(n0 + r) * FH + j;
  const size_t NF = (size_t)NN * FH;
  float pre = b1[j];
#pragma unroll
  for (int s = 0; s < SPLIT1; ++s) pre += hpart[idx + (size_t)s * NF];
  float v = fmaxf(pre, 0.0f) * dropout_scale(idx);
  hl[r][j] = v;
  __syncthreads();
  if (t < 64) {
    const int rr = t >> 4, f = t & 15;
    float s = 0.f;
#pragma unroll 8
    for (int jj = 0; jj < FH; ++jj)
      s = fmaf(hl[rr][jj], W2l[jj * FO + f], s);
    HWT[(size_t)f * NN + (n0 + rr)] = (_Float16)s;
  }
}

// ===== pass 2 (dot2): out += A2q(fp8, regs) @ HWT(fp16, LDS) =====
__global__ __launch_bounds__(64) void k_pass2_dot(const uint32_t* __restrict__ A2q,
                                                  const _Float16* __restrict__ HWT,
                                                  float* __restrict__ out) {
  __shared__ f16x8 Htl[64 * 16];   // 16 KB
  const int t = threadIdx.x;       // 0..63
  const int mb = blockIdx.x >> 4;  // 0..127
  const int sp = blockIdx.x & 15;  // 0..15
  const size_t row0 = (size_t)mb * BM;
  const int nbase = sp * NRANGE2;
  const size_t NNq = (size_t)NN / 4;

#pragma unroll
  for (int i = 0; i < FO; ++i)
    Htl[t * FO + i] = *(const f16x8*)(HWT + (size_t)i * NN + nbase + t * 8);
  __syncthreads();

  const int fgrp = t & 3;
  const int mgrp = t >> 2;
  const size_t rbase = (row0 + (size_t)mgrp * 4) * NNq + (size_t)(nbase >> 2);

  float acc[4][4];
#pragma unroll
  for (int j = 0; j < 4; ++j)
#pragma unroll
    for (int i = 0; i < 4; ++i) acc[j][i] = 0.f;

  uint2 aA[4], aB[4];
#pragma unroll
  for (int j = 0; j < 4; ++j)
    aA[j] = *(const uint2*)(A2q + rbase + (size_t)j * NNq);

  auto LOADB = [&](int o) {
#pragma unroll
    for (int j = 0; j < 4; ++j)
      aB[j] = *(const uint2*)(A2q + rbase + (size_t)j * NNq + o * 2);
  };
  auto LOADA = [&](int o) {
#pragma unroll
    for (int j = 0; j < 4; ++j)
      aA[j] = *(const uint2*)(A2q + rbase + (size_t)j * NNq + o * 2);
  };

  auto COMPUTE = [&](const uint2* buf, int o) {
    U8 h0, h1, h2v, h3;
    h0.v  = Htl[o * FO + fgrp * 4 + 0];
    h1.v  = Htl[o * FO + fgrp * 4 + 1];
    h2v.v = Htl[o * FO + fgrp * 4 + 2];
    h3.v  = Htl[o * FO + fgrp * 4 + 3];
#pragma unroll
    for (int j = 0; j < 4; ++j) {
      U8 a;
      a.v = dec8_fp8(buf[j]);
#pragma unroll
      for (int q = 0; q < 4; ++q) {
        h2 pa = a.p[q];
        acc[j][0] = dot2(pa, h0.p[q],  acc[j][0]);
        acc[j][1] = dot2(pa, h1.p[q],  acc[j][1]);
        acc[j][2] = dot2(pa, h2v.p[q], acc[j][2]);
        acc[j][3] = dot2(pa, h3.p[q],  acc[j][3]);
      }
    }
  };

  for (int o = 0; o < 64; o += 2) {
    LOADB(o + 1);
    COMPUTE(aA, o);
    if (o + 2 < 64) LOADA(o + 2);
    COMPUTE(aB, o + 1);
  }

#pragma unroll
  for (int j = 0; j < 4; ++j)
#pragma unroll
    for (int i = 0; i < 4; ++i)
      atomicAdd(&out[(row0 + (size_t)mgrp * 4 + j) * FO + fgrp * 4 + i], acc[j][i]);
}

extern "C" void kernel_launch(void* const* d_in, const int* in_sizes, int n_in,
                              void* d_out, int out_size, void* d_ws, size_t ws_size,
                              hipStream_t stream) {
  const float* adj = (const float*)d_in[0];
  const float* x   = (const float*)d_in[1];
  const float* W1  = (const float*)d_in[2];
  const float* b1  = (const float*)d_in[3];
  const float* W2  = (const float*)d_in[4];
  const float* b2  = (const float*)d_in[5];
  const float* pi1 = (const float*)d_in[6];
  const float* pi2 = (const float*)d_in[7];
  float* out = (float*)d_out;
  float* ws  = (float*)d_ws;

  // ws layout: hpart f32[4*NN*FH] | S1p fp16[NN*FH] | A2q u32[NN*NN/4] | HWT fp16[FO*NN]  (~76 MB)
  float* hpart  = ws;
  _Float16* S1p = (_Float16*)(hpart + (size_t)SPLIT1 * NN * FH);
  uint32_t* A2q = (uint32_t*)(S1p + (size_t)NN * FH);
  _Float16* HWT = (_Float16*)(A2q + (size_t)NN * NN / 4);

  k_s1         <<<NN / 16,            256, 0, stream>>>(x, W1, S1p);
  k_pass1_fused<<<(NN / BM) * SPLIT1, 256, 0, stream>>>(adj, S1p, pi1, pi2, hpart, A2q);
  k_mid        <<<NN / 4,             256, 0, stream>>>(hpart, b1, W2, b2, HWT, out);
  k_pass2_dot  <<<(NN / BM) * SPLIT2,  64, 0, stream>>>(A2q, HWT, out);
}